// Round 6
// baseline (585.669 us; speedup 1.0000x reference)
//
#include <hip/hip_runtime.h>

#define B_ROWS   131072
#define MTILE    64
#define KCHUNKS  17        // 544 / 32
#define LDA      552       // At leading dim f16: 544+8 pad
#define LDX      528       // X2 leading dim f16: 512+16 pad
// ws layout: [0,128KB) mask u8; [128KB,+557056) W1f f16 [544 frags][512]; then W2f f16 [16][512]
#define W1F_OFF  ((size_t)B_ROWS)
#define W2F_OFF  (W1F_OFF + (size_t)544 * 512 * 2)

typedef _Float16 f16x8 __attribute__((ext_vector_type(8)));
typedef float    f32x4 __attribute__((ext_vector_type(4)));

__device__ inline unsigned short f2h(float f) {
  _Float16 h = (_Float16)f;
  return __builtin_bit_cast(unsigned short, h);
}
__device__ inline float selu_f(float x) {
  const float lam = 1.0507009873554805f, alp = 1.6732632423543772f;
  return x > 0.f ? lam * x : lam * alp * (__expf(x) - 1.f);
}

__global__ void scatter_mask(const int* __restrict__ coords,
                             unsigned char* __restrict__ mask) {
  int i = blockIdx.x * 256 + threadIdx.x;
  mask[coords[i]] = 1u;
}

// Blocks 0..543: W1 fp32 [526][512] -> W1f f16 pre-fragmented, per-wave MFMA order:
//   frag = (wq*17 + c)*4 + ni;  W1f[frag*512 + lane*8 + e] = W1[k-perm][n]
//   n = wq*64+ni*16+(lane&15), k = c*32+(lane>>4)*8+e
//   K-perm: k<512 -> orig row k+14; 512<=k<526 -> jnt rows k-512; else 0.
// Blocks 544..559: W2 fp32 [512][7] -> W2f f16 [16 kchunks][512], n padded to 16.
__global__ void build_wf(const float* __restrict__ W1, const float* __restrict__ W2,
                         unsigned short* __restrict__ W1f, unsigned short* __restrict__ W2f) {
  int tid = threadIdx.x;               // 0..511
  if (blockIdx.x < 544) {
    int fragIdx = blockIdx.x;
    int ni = fragIdx & 3;
    int c  = (fragIdx >> 2) % 17;
    int wq = fragIdx / 68;
    int nbase = wq * 64 + ni * 16;
    __shared__ float t[32][17];        // [k_local][n_local], +1 pad
    int kl = tid >> 4, nl = tid & 15;  // coalesced read: consecutive tid -> consecutive n
    int kg = c * 32 + kl;
    float v = 0.f;
    if (kg < 512)      v = W1[(size_t)(kg + 14) * 512 + nbase + nl];
    else if (kg < 526) v = W1[(size_t)(kg - 512) * 512 + nbase + nl];
    t[kl][nl] = v;
    __syncthreads();
    int lane = tid >> 3, e = tid & 7;
    int k2 = ((lane >> 4) & 3) * 8 + e;
    int n2 = lane & 15;
    W1f[(size_t)fragIdx * 512 + tid] = f2h(t[k2][n2]);
  } else {
    int c2 = blockIdx.x - 544;         // 0..15
    int lane = tid >> 3, e = tid & 7;
    int n = lane & 15, quad = (lane >> 4) & 3;
    int k = c2 * 32 + quad * 8 + e;
    float v = (n < 7) ? W2[(size_t)k * 7 + n] : 0.f;
    W2f[(size_t)c2 * 512 + tid] = f2h(v);
  }
}

struct __align__(16) SMem {
  // union: At[64][552] f16 = 70656B (K loop)
  //        X2[64][528] f16 = 67584B + O[64][8] f32 = 2048B -> 69632B (epilogue)
  char buf[70656];
  float part[8][MTILE][2];   // per-wave LN2 partial s,q
  float mean2[MTILE], rstd2[MTILE];
};

__global__ __launch_bounds__(512, 4) void actor_main(
    const float* __restrict__ feat, const unsigned char* __restrict__ mask,
    const float* __restrict__ jp, const float* __restrict__ jg,
    const float* __restrict__ ln1g, const float* __restrict__ ln1b,
    const unsigned short* __restrict__ W1f, const float* __restrict__ b1,
    const float* __restrict__ ln2g, const float* __restrict__ ln2b,
    const unsigned short* __restrict__ W2f, const float* __restrict__ b2,
    float* __restrict__ out) {
  __shared__ SMem sm;
  unsigned short* At = (unsigned short*)sm.buf;            // [64][LDA] f16
  unsigned short* X2 = (unsigned short*)sm.buf;            // [64][LDX] f16 (epilogue union)
  float*          O  = (float*)(sm.buf + 64 * LDX * 2);    // [64][8] f32

  const int tid  = threadIdx.x;
  const int wq   = tid >> 6;   // wave 0..7 = N-slice (64 cols each)
  const int lane = tid & 63;
  const int m0   = blockIdx.x * MTILE;
  const int mrow = lane & 15;
  const int quad = lane >> 4;

  // ---------- A build: 16 threads/row, two sequential half-tiles ----------
  // Thread (r16=tid>>4, t16=tid&15): row m0+r16(+32), float4 cols {t16 + j*16}.
  // Single pass: stats from f32 regs (one rounding), f[8]=32 VGPR peak.
  auto buildHalf = [&](int arow_h) {
    const int t16 = tid & 15;
    const int row = m0 + arow_h;
    float mk = mask[row] ? 1.f : 0.f;  // masked-out row => y=0 => LN -> b -> selu(b)
    const float4* frow = (const float4*)feat + (size_t)row * 128;
    float4 f[8];
    float s = 0.f, q = 0.f;
#pragma unroll
    for (int j = 0; j < 8; ++j) {
      float4 v = frow[t16 + j * 16];   // per j: 16 lanes read 256B contiguous
      f[j] = v;
      s += v.x + v.y + v.z + v.w;
      q += v.x * v.x + v.y * v.y + v.z * v.z + v.w * v.w;
    }
    s += __shfl_xor(s, 1); q += __shfl_xor(q, 1);
    s += __shfl_xor(s, 2); q += __shfl_xor(q, 2);
    s += __shfl_xor(s, 4); q += __shfl_xor(q, 4);
    s += __shfl_xor(s, 8); q += __shfl_xor(q, 8);
    float mean = mk * s * (1.f / 512.f);
    float msq  = mk * q * (1.f / 512.f);
    float rstd = rsqrtf(msq - mean * mean + 1e-5f);
#pragma unroll 2
    for (int j = 0; j < 8; ++j) {      // unroll 2: <=4 g/b float4 in flight
      float4 g = ((const float4*)ln1g)[t16 + j * 16];
      float4 b = ((const float4*)ln1b)[t16 + j * 16];
      union { unsigned short us[4]; uint2 u; } pk;
      pk.us[0] = f2h(selu_f((f[j].x * mk - mean) * rstd * g.x + b.x));
      pk.us[1] = f2h(selu_f((f[j].y * mk - mean) * rstd * g.y + b.y));
      pk.us[2] = f2h(selu_f((f[j].z * mk - mean) * rstd * g.z + b.z));
      pk.us[3] = f2h(selu_f((f[j].w * mk - mean) * rstd * g.w + b.w));
      *(uint2*)&At[arow_h * LDA + j * 64 + t16 * 4] = pk.u;
    }
    {  // jnt cols 512..543: 2 cols/thread (jp[0..7), jg[7..14), zero pad)
      int kk = 2 * t16;
      float v0 = 0.f, v1 = 0.f;
      if (kk < 7)       v0 = jp[(size_t)row * 7 + kk];
      else if (kk < 14) v0 = jg[(size_t)row * 7 + kk - 7];
      if (kk + 1 < 7)       v1 = jp[(size_t)row * 7 + kk + 1];
      else if (kk + 1 < 14) v1 = jg[(size_t)row * 7 + kk - 6];
      union { unsigned short us[2]; unsigned int u; } pj;
      pj.us[0] = f2h(v0); pj.us[1] = f2h(v1);
      *(unsigned int*)&At[arow_h * LDA + 512 + 2 * t16] = pj.u;
    }
  };
  buildHalf(tid >> 4);
  __builtin_amdgcn_sched_barrier(0);   // keep halves sequential (pressure cap)
  buildHalf((tid >> 4) + 32);

  // ---------- B chunk-0 prefetch (after A-build; doesn't pressure it) ----------
  const unsigned short* wBase = W1f + (size_t)wq * 68 * 512 + lane * 8;
  f16x8 bE[4], bO[4];
#pragma unroll
  for (int ni = 0; ni < 4; ++ni)
    bE[ni] = *(const f16x8*)(wBase + (size_t)ni * 512);

  __syncthreads();  // barrier #1 (only one before K loop)

  // ---------- K loop: barrier-free, pre-fragmented B, reg ping-pong ----------
  f32x4 acc[4][4];
#pragma unroll
  for (int mi = 0; mi < 4; ++mi)
#pragma unroll
    for (int ni = 0; ni < 4; ++ni) acc[mi][ni] = (f32x4){0.f, 0.f, 0.f, 0.f};

  const unsigned short* aB = At + mrow * LDA + quad * 8;

  auto loadB = [&](f16x8* dst, int c) {
#pragma unroll
    for (int ni = 0; ni < 4; ++ni)
      dst[ni] = *(const f16x8*)(wBase + (size_t)(c * 4 + ni) * 512);
  };
  auto step = [&](const f16x8* bF, int c) {
    f16x8 a[4];
#pragma unroll
    for (int mi = 0; mi < 4; ++mi)
      a[mi] = *(const f16x8*)(aB + mi * 16 * LDA + c * 32);
#pragma unroll
    for (int mi = 0; mi < 4; ++mi)
#pragma unroll
      for (int ni = 0; ni < 4; ++ni)
        acc[mi][ni] = __builtin_amdgcn_mfma_f32_16x16x32_f16(a[mi], bF[ni], acc[mi][ni], 0, 0, 0);
  };

  for (int c = 0; c < KCHUNKS - 1; c += 2) {  // c = 0,2,...,14
    loadB(bO, c + 1);
    step(bE, c);
    loadB(bE, c + 2);                         // c+2 <= 16, valid
    step(bO, c + 1);
  }
  step(bE, 16);

  // ---------- GEMM2 B-frag prefetch (wave's own K-slice k = wq*64..+64) ----------
  f16x8 bW2[2];
  bW2[0] = *(const f16x8*)&W2f[(size_t)(2 * wq)     * 512 + lane * 8];
  bW2[1] = *(const f16x8*)&W2f[(size_t)(2 * wq + 1) * 512 + lane * 8];

  // ---------- epilogue: +b1, LN2 stats (per-wave partials, no atomics) ----------
  float b1v[4], g2v[4], bl2v[4];
#pragma unroll
  for (int ni = 0; ni < 4; ++ni) {
    int col = wq * 64 + ni * 16 + mrow;
    b1v[ni] = b1[col]; g2v[ni] = ln2g[col]; bl2v[ni] = ln2b[col];
  }
#pragma unroll
  for (int mi = 0; mi < 4; ++mi)
#pragma unroll
    for (int reg = 0; reg < 4; ++reg) {
      int r = mi * 16 + quad * 4 + reg;  // C/D layout: col=lane&15, row=quad*4+reg
      float s = 0.f, q = 0.f;
#pragma unroll
      for (int ni = 0; ni < 4; ++ni) {
        float v = acc[mi][ni][reg] + b1v[ni];
        acc[mi][ni][reg] = v;
        s += v; q += v * v;
      }
      s += __shfl_xor(s, 1); q += __shfl_xor(q, 1);
      s += __shfl_xor(s, 2); q += __shfl_xor(q, 2);
      s += __shfl_xor(s, 4); q += __shfl_xor(q, 4);
      s += __shfl_xor(s, 8); q += __shfl_xor(q, 8);
      if ((lane & 15) == 0) { sm.part[wq][r][0] = s; sm.part[wq][r][1] = q; }
    }
  __syncthreads();  // barrier #2: K-loop At reads done; partials complete
  if (tid < MTILE) {
    float s = 0.f, q = 0.f;
#pragma unroll
    for (int w = 0; w < 8; ++w) { s += sm.part[w][tid][0]; q += sm.part[w][tid][1]; }
    float mean = s * (1.f / 512.f);
    float var  = q * (1.f / 512.f) - mean * mean;
    sm.mean2[tid] = mean;
    sm.rstd2[tid] = rsqrtf(var + 1e-5f);
  }
  O[tid] = 0.f;     // 64x8 = 512 floats, region beyond X2, At dead
  __syncthreads();  // barrier #3: mean2/rstd2 + O ready
#pragma unroll
  for (int mi = 0; mi < 4; ++mi)
#pragma unroll
    for (int ni = 0; ni < 4; ++ni)
#pragma unroll
      for (int reg = 0; reg < 4; ++reg) {
        int r = mi * 16 + quad * 4 + reg;
        int col = wq * 64 + ni * 16 + mrow;
        float v = (acc[mi][ni][reg] - sm.mean2[r]) * sm.rstd2[r] * g2v[ni] + bl2v[ni];
        X2[r * LDX + col] = f2h(selu_f(v));
      }
  __syncthreads();  // barrier #4: X2 complete

  // ---------- GEMM2 (512->7) via MFMA, K-split across waves, LDS f32 reduce ----------
  {
    f32x4 acc2[4];
#pragma unroll
    for (int mi = 0; mi < 4; ++mi) acc2[mi] = (f32x4){0.f, 0.f, 0.f, 0.f};
#pragma unroll
    for (int j = 0; j < 2; ++j) {
      int c2 = 2 * wq + j;
#pragma unroll
      for (int mi = 0; mi < 4; ++mi) {
        f16x8 a = *(const f16x8*)&X2[(mi * 16 + mrow) * LDX + c2 * 32 + quad * 8];
        acc2[mi] = __builtin_amdgcn_mfma_f32_16x16x32_f16(a, bW2[j], acc2[mi], 0, 0, 0);
      }
    }
#pragma unroll
    for (int mi = 0; mi < 4; ++mi)
#pragma unroll
      for (int reg = 0; reg < 4; ++reg)
        if (mrow < 7)
          atomicAdd(&O[(mi * 16 + quad * 4 + reg) * 8 + mrow], acc2[mi][reg]);
  }
  __syncthreads();  // barrier #5: O complete
  {
    int r = tid >> 3, c = tid & 7;
    if (c < 7)
      out[(size_t)(m0 + r) * 7 + c] = tanhf(O[tid] + b2[c]);
  }
}

extern "C" void kernel_launch(void* const* d_in, const int* in_sizes, int n_in,
                              void* d_out, int out_size, void* d_ws, size_t ws_size,
                              hipStream_t stream) {
  const float* feat  = (const float*)d_in[0];
  const int*   crd   = (const int*)d_in[1];
  const float* jp    = (const float*)d_in[2];
  const float* jg    = (const float*)d_in[3];
  const float* ln1g  = (const float*)d_in[4];
  const float* ln1b  = (const float*)d_in[5];
  const float* W1    = (const float*)d_in[6];
  const float* b1    = (const float*)d_in[7];
  const float* ln2g  = (const float*)d_in[8];
  const float* ln2b  = (const float*)d_in[9];
  const float* W2    = (const float*)d_in[10];
  const float* b2    = (const float*)d_in[11];
  float* out = (float*)d_out;

  unsigned char*  mask = (unsigned char*)d_ws;
  unsigned short* W1f  = (unsigned short*)((char*)d_ws + W1F_OFF);
  unsigned short* W2f  = (unsigned short*)((char*)d_ws + W2F_OFF);

  hipMemsetAsync(mask, 0, (size_t)B_ROWS, stream);
  scatter_mask<<<B_ROWS / 256, 256, 0, stream>>>(crd, mask);
  build_wf<<<560, 512, 0, stream>>>(W1, W2, W1f, W2f);
  actor_main<<<B_ROWS / MTILE, 512, 0, stream>>>(
      feat, mask, jp, jg, ln1g, ln1b, W1f, b1, ln2g, ln2b, W2f, b2, out);
}

// Round 7
// 550.870 us; speedup vs baseline: 1.0632x; 1.0632x over previous
//
#include <hip/hip_runtime.h>

#define B_ROWS   131072
#define MTILE    64
#define KCHUNKS  17        // 544 / 32
#define LDA      552       // row stride f16: 544+8 pad (1104B: 16B-aligned, 2-way LDS banks)
#define LDX      528       // X2 leading dim f16: 512+16 pad
// ws layout: [0,128KB) mask u8; W1f f16 [544 frags][512]; W2f f16 [16][512]; X1 f16 [B][552]
#define W1F_OFF  ((size_t)B_ROWS)
#define W2F_OFF  (W1F_OFF + (size_t)544 * 512 * 2)
#define X1_OFF   (W2F_OFF + (size_t)16 * 512 * 2)
#define X1_BYTES ((size_t)B_ROWS * LDA * 2)

typedef _Float16 f16x8 __attribute__((ext_vector_type(8)));
typedef float    f32x4 __attribute__((ext_vector_type(4)));

__device__ inline unsigned short f2h(float f) {
  _Float16 h = (_Float16)f;
  return __builtin_bit_cast(unsigned short, h);
}
__device__ inline float selu_f(float x) {
  const float lam = 1.0507009873554805f, alp = 1.6732632423543772f;
  return x > 0.f ? lam * x : lam * alp * (__expf(x) - 1.f);
}
__device__ inline void gld16(const void* g, void* l) {
  __builtin_amdgcn_global_load_lds(
      (const __attribute__((address_space(1))) unsigned int*)g,
      (__attribute__((address_space(3))) unsigned int*)l, 16, 0, 0);
}

__global__ void scatter_mask(const int* __restrict__ coords,
                             unsigned char* __restrict__ mask) {
  int i = blockIdx.x * 256 + threadIdx.x;
  mask[coords[i]] = 1u;
}

// Blocks 0..543: W1 fp32 [526][512] -> W1f f16 pre-fragmented, per-wave MFMA order.
// Blocks 544..559: W2 fp32 [512][7] -> W2f f16 [16 kchunks][512], n padded to 16.
__global__ void build_wf(const float* __restrict__ W1, const float* __restrict__ W2,
                         unsigned short* __restrict__ W1f, unsigned short* __restrict__ W2f) {
  int tid = threadIdx.x;               // 0..511
  if (blockIdx.x < 544) {
    int fragIdx = blockIdx.x;
    int ni = fragIdx & 3;
    int c  = (fragIdx >> 2) % 17;
    int wq = fragIdx / 68;
    int nbase = wq * 64 + ni * 16;
    __shared__ float t[32][17];        // [k_local][n_local], +1 pad
    int kl = tid >> 4, nl = tid & 15;  // coalesced read side
    int kg = c * 32 + kl;
    float v = 0.f;
    if (kg < 512)      v = W1[(size_t)(kg + 14) * 512 + nbase + nl];
    else if (kg < 526) v = W1[(size_t)(kg - 512) * 512 + nbase + nl];
    t[kl][nl] = v;
    __syncthreads();
    int lane = tid >> 3, e = tid & 7;
    int k2 = ((lane >> 4) & 3) * 8 + e;
    int n2 = lane & 15;
    W1f[(size_t)fragIdx * 512 + tid] = f2h(t[k2][n2]);
  } else {
    int c2 = blockIdx.x - 544;         // 0..15
    int lane = tid >> 3, e = tid & 7;
    int n = lane & 15, quad = (lane >> 4) & 3;
    int k = c2 * 32 + quad * 8 + e;
    float v = (n < 7) ? W2[(size_t)k * 7 + n] : 0.f;
    W2f[(size_t)c2 * 512 + tid] = f2h(v);
  }
}

// ---------------- split path kernel 1: LN1+SELU+concat -> X1 f16 [B][552] ----------------
// One wave per row. No MFMA -> no AGPR reservation -> ~30 live regs, no spill possible.
__global__ __launch_bounds__(512) void ln1_kernel(
    const float* __restrict__ feat, const unsigned char* __restrict__ mask,
    const float* __restrict__ jp, const float* __restrict__ jg,
    const float* __restrict__ ln1g, const float* __restrict__ ln1b,
    unsigned short* __restrict__ X1) {
  const int w = threadIdx.x >> 6, lane = threadIdx.x & 63;
  const size_t row = (size_t)blockIdx.x * 8 + w;
  float mk = mask[row] ? 1.f : 0.f;    // masked-out row => y=0 => LN -> b -> selu(b)
  const float4* frow = (const float4*)feat + row * 128;
  float4 f0 = frow[lane];              // cols 4*lane..+4
  float4 f1 = frow[64 + lane];         // cols 256+4*lane..+4
  float s = f0.x + f0.y + f0.z + f0.w + f1.x + f1.y + f1.z + f1.w;
  float q = f0.x * f0.x + f0.y * f0.y + f0.z * f0.z + f0.w * f0.w +
            f1.x * f1.x + f1.y * f1.y + f1.z * f1.z + f1.w * f1.w;
#pragma unroll
  for (int d = 32; d > 0; d >>= 1) { s += __shfl_xor(s, d); q += __shfl_xor(q, d); }
  float mean = mk * s * (1.f / 512.f);
  float msq  = mk * q * (1.f / 512.f);
  float rstd = rsqrtf(msq - mean * mean + 1e-5f);
  unsigned short* xr = X1 + row * LDA;
  {
    float4 g = ((const float4*)ln1g)[lane], b = ((const float4*)ln1b)[lane];
    union { unsigned short us[4]; uint2 u; } pk;
    pk.us[0] = f2h(selu_f((f0.x * mk - mean) * rstd * g.x + b.x));
    pk.us[1] = f2h(selu_f((f0.y * mk - mean) * rstd * g.y + b.y));
    pk.us[2] = f2h(selu_f((f0.z * mk - mean) * rstd * g.z + b.z));
    pk.us[3] = f2h(selu_f((f0.w * mk - mean) * rstd * g.w + b.w));
    *(uint2*)&xr[lane * 4] = pk.u;
  }
  {
    float4 g = ((const float4*)ln1g)[64 + lane], b = ((const float4*)ln1b)[64 + lane];
    union { unsigned short us[4]; uint2 u; } pk;
    pk.us[0] = f2h(selu_f((f1.x * mk - mean) * rstd * g.x + b.x));
    pk.us[1] = f2h(selu_f((f1.y * mk - mean) * rstd * g.y + b.y));
    pk.us[2] = f2h(selu_f((f1.z * mk - mean) * rstd * g.z + b.z));
    pk.us[3] = f2h(selu_f((f1.w * mk - mean) * rstd * g.w + b.w));
    *(uint2*)&xr[256 + lane * 4] = pk.u;
  }
  if (lane < 16) {       // jnt cols 512..543: jp[0..7), jg[7..14), zero pad
    int kk = 2 * lane;
    float v0 = 0.f, v1 = 0.f;
    if (kk < 7)       v0 = jp[row * 7 + kk];
    else if (kk < 14) v0 = jg[row * 7 + kk - 7];
    if (kk + 1 < 7)       v1 = jp[row * 7 + kk + 1];
    else if (kk + 1 < 14) v1 = jg[row * 7 + kk - 6];
    union { unsigned short us[2]; unsigned int u; } pj;
    pj.us[0] = f2h(v0); pj.us[1] = f2h(v1);
    *(unsigned int*)&xr[512 + 2 * lane] = pj.u;
  } else if (lane < 20) {  // zero the 544..551 pad (staged into LDS, never consumed)
    *(unsigned int*)&xr[544 + 2 * (lane - 16)] = 0u;
  }
}

// ---------------- split path kernel 2: GEMM1 + LN2 + SELU + GEMM2 + tanh ----------------
struct __align__(16) SMemG {
  // union: At[64][552] f16 = 70656B (K loop; staged linearly via global_load_lds)
  //        X2[64][528] f16 = 67584B + O[64][8] f32 = 2048B (epilogue)
  char buf[70656];
  float part[8][MTILE][2];   // per-wave LN2 partial s,q
  float mean2[MTILE], rstd2[MTILE];
};

__global__ __launch_bounds__(512, 4) void actor_gemm(
    const unsigned short* __restrict__ X1,
    const unsigned short* __restrict__ W1f, const float* __restrict__ b1,
    const float* __restrict__ ln2g, const float* __restrict__ ln2b,
    const unsigned short* __restrict__ W2f, const float* __restrict__ b2,
    float* __restrict__ out) {
  __shared__ SMemG sm;
  unsigned short* At = (unsigned short*)sm.buf;            // [64][LDA] f16
  unsigned short* X2 = (unsigned short*)sm.buf;            // [64][LDX] f16 (epilogue union)
  float*          O  = (float*)(sm.buf + 64 * LDX * 2);    // [64][8] f32

  const int tid  = threadIdx.x;
  const int wq   = tid >> 6;   // wave 0..7 = N-slice (64 cols each)
  const int lane = tid & 63;
  const int m0   = blockIdx.x * MTILE;
  const int mrow = lane & 15;
  const int quad = lane >> 4;

  // ---------- A staging: linear 70656B copy, 69 wave-chunks of 1KB, zero VALU ----------
  {
    const char* src = (const char*)X1 + (size_t)m0 * (LDA * 2);
#pragma unroll
    for (int i = 0; i < 8; ++i) {
      int chunk = i * 8 + wq;
      gld16(src + (size_t)chunk * 1024 + lane * 16, (char*)sm.buf + chunk * 1024);
    }
    if (wq < 5) {
      int chunk = 64 + wq;
      gld16(src + (size_t)chunk * 1024 + lane * 16, (char*)sm.buf + chunk * 1024);
    }
  }

  // ---------- B chunk-0 prefetch (in flight alongside staging) ----------
  const unsigned short* wBase = W1f + (size_t)wq * 68 * 512 + lane * 8;
  f16x8 bE[4], bO[4];
#pragma unroll
  for (int ni = 0; ni < 4; ++ni)
    bE[ni] = *(const f16x8*)(wBase + (size_t)ni * 512);

  __syncthreads();  // barrier #1: staging (vmcnt drain) complete

  // ---------- K loop: barrier-free, pre-fragmented B, reg ping-pong ----------
  f32x4 acc[4][4];
#pragma unroll
  for (int mi = 0; mi < 4; ++mi)
#pragma unroll
    for (int ni = 0; ni < 4; ++ni) acc[mi][ni] = (f32x4){0.f, 0.f, 0.f, 0.f};

  const unsigned short* aB = At + mrow * LDA + quad * 8;

  auto loadB = [&](f16x8* dst, int c) {
#pragma unroll
    for (int ni = 0; ni < 4; ++ni)
      dst[ni] = *(const f16x8*)(wBase + (size_t)(c * 4 + ni) * 512);
  };
  auto step = [&](const f16x8* bF, int c) {
    f16x8 a[4];
#pragma unroll
    for (int mi = 0; mi < 4; ++mi)
      a[mi] = *(const f16x8*)(aB + mi * 16 * LDA + c * 32);
#pragma unroll
    for (int mi = 0; mi < 4; ++mi)
#pragma unroll
      for (int ni = 0; ni < 4; ++ni)
        acc[mi][ni] = __builtin_amdgcn_mfma_f32_16x16x32_f16(a[mi], bF[ni], acc[mi][ni], 0, 0, 0);
  };

  for (int c = 0; c < KCHUNKS - 1; c += 2) {  // c = 0,2,...,14
    loadB(bO, c + 1);
    step(bE, c);
    loadB(bE, c + 2);                         // c+2 <= 16, valid
    step(bO, c + 1);
  }
  step(bE, 16);

  // ---------- GEMM2 B-frag prefetch (wave's own K-slice k = wq*64..+64) ----------
  f16x8 bW2[2];
  bW2[0] = *(const f16x8*)&W2f[(size_t)(2 * wq)     * 512 + lane * 8];
  bW2[1] = *(const f16x8*)&W2f[(size_t)(2 * wq + 1) * 512 + lane * 8];

  // ---------- epilogue: +b1, LN2 stats (per-wave partials) ----------
  float b1v[4], g2v[4], bl2v[4];
#pragma unroll
  for (int ni = 0; ni < 4; ++ni) {
    int col = wq * 64 + ni * 16 + mrow;
    b1v[ni] = b1[col]; g2v[ni] = ln2g[col]; bl2v[ni] = ln2b[col];
  }
#pragma unroll
  for (int mi = 0; mi < 4; ++mi)
#pragma unroll
    for (int reg = 0; reg < 4; ++reg) {
      int r = mi * 16 + quad * 4 + reg;  // C/D layout: col=lane&15, row=quad*4+reg
      float s = 0.f, q = 0.f;
#pragma unroll
      for (int ni = 0; ni < 4; ++ni) {
        float v = acc[mi][ni][reg] + b1v[ni];
        acc[mi][ni][reg] = v;
        s += v; q += v * v;
      }
      s += __shfl_xor(s, 1); q += __shfl_xor(q, 1);
      s += __shfl_xor(s, 2); q += __shfl_xor(q, 2);
      s += __shfl_xor(s, 4); q += __shfl_xor(q, 4);
      s += __shfl_xor(s, 8); q += __shfl_xor(q, 8);
      if ((lane & 15) == 0) { sm.part[wq][r][0] = s; sm.part[wq][r][1] = q; }
    }
  __syncthreads();  // barrier #2: K-loop At reads done; partials complete
  if (tid < MTILE) {
    float s = 0.f, q = 0.f;
#pragma unroll
    for (int w = 0; w < 8; ++w) { s += sm.part[w][tid][0]; q += sm.part[w][tid][1]; }
    float mean = s * (1.f / 512.f);
    float var  = q * (1.f / 512.f) - mean * mean;
    sm.mean2[tid] = mean;
    sm.rstd2[tid] = rsqrtf(var + 1e-5f);
  }
  O[tid] = 0.f;     // 64x8 floats, region beyond X2, At dead
  __syncthreads();  // barrier #3: mean2/rstd2 + O ready
#pragma unroll
  for (int mi = 0; mi < 4; ++mi)
#pragma unroll
    for (int ni = 0; ni < 4; ++ni)
#pragma unroll
      for (int reg = 0; reg < 4; ++reg) {
        int r = mi * 16 + quad * 4 + reg;
        int col = wq * 64 + ni * 16 + mrow;
        float v = (acc[mi][ni][reg] - sm.mean2[r]) * sm.rstd2[r] * g2v[ni] + bl2v[ni];
        X2[r * LDX + col] = f2h(selu_f(v));
      }
  __syncthreads();  // barrier #4: X2 complete

  // ---------- GEMM2 (512->7) via MFMA, K-split across waves, LDS f32 reduce ----------
  {
    f32x4 acc2[4];
#pragma unroll
    for (int mi = 0; mi < 4; ++mi) acc2[mi] = (f32x4){0.f, 0.f, 0.f, 0.f};
#pragma unroll
    for (int j = 0; j < 2; ++j) {
      int c2 = 2 * wq + j;
#pragma unroll
      for (int mi = 0; mi < 4; ++mi) {
        f16x8 a = *(const f16x8*)&X2[(mi * 16 + mrow) * LDX + c2 * 32 + quad * 8];
        acc2[mi] = __builtin_amdgcn_mfma_f32_16x16x32_f16(a, bW2[j], acc2[mi], 0, 0, 0);
      }
    }
#pragma unroll
    for (int mi = 0; mi < 4; ++mi)
#pragma unroll
      for (int reg = 0; reg < 4; ++reg)
        if (mrow < 7)
          atomicAdd(&O[(mi * 16 + quad * 4 + reg) * 8 + mrow], acc2[mi][reg]);
  }
  __syncthreads();  // barrier #5: O complete
  {
    int r = tid >> 3, c = tid & 7;
    if (c < 7)
      out[(size_t)(m0 + r) * 7 + c] = tanhf(O[tid] + b2[c]);
  }
}

// ---------------- fallback: R4-verbatim fused kernel (used if ws too small for X1) ----------------
struct __align__(16) SMemF {
  char buf[70656];
  float rsum[MTILE], rsq[MTILE], mean2[MTILE], rstd2[MTILE];
};

__global__ __launch_bounds__(512, 4) void actor_fused(
    const float* __restrict__ feat, const unsigned char* __restrict__ mask,
    const float* __restrict__ jp, const float* __restrict__ jg,
    const float* __restrict__ ln1g, const float* __restrict__ ln1b,
    const unsigned short* __restrict__ W1f, const float* __restrict__ b1,
    const float* __restrict__ ln2g, const float* __restrict__ ln2b,
    const unsigned short* __restrict__ W2f, const float* __restrict__ b2,
    float* __restrict__ out) {
  __shared__ SMemF sm;
  unsigned short* At = (unsigned short*)sm.buf;
  unsigned short* X2 = (unsigned short*)sm.buf;
  float*          O  = (float*)(sm.buf + 64 * LDX * 2);

  const int tid  = threadIdx.x;
  const int wq   = tid >> 6;
  const int lane = tid & 63;
  const int m0   = blockIdx.x * MTILE;
  const int mrow = lane & 15;
  const int quad = lane >> 4;

  if (tid < MTILE) { sm.rsum[tid] = 0.f; sm.rsq[tid] = 0.f; }

  const unsigned short* wBase = W1f + (size_t)wq * 68 * 512 + lane * 8;
  f16x8 bE[4], bO[4];
#pragma unroll
  for (int ni = 0; ni < 4; ++ni)
    bE[ni] = *(const f16x8*)(wBase + (size_t)ni * 512);

  {
    const int arow = tid >> 3;
    const int acg  = tid & 7;
    const int row  = m0 + arow;
    const float4* frow = (const float4*)feat + (size_t)row * 128 + acg;
    float4 f[16];
    float s = 0.f, q = 0.f;
#pragma unroll
    for (int c = 0; c < 16; ++c) {
      float4 v = frow[(size_t)c * 8];
      f[c] = v;
      s += v.x + v.y + v.z + v.w;
      q += v.x * v.x + v.y * v.y + v.z * v.z + v.w * v.w;
    }
    s += __shfl_xor(s, 1); q += __shfl_xor(q, 1);
    s += __shfl_xor(s, 2); q += __shfl_xor(q, 2);
    s += __shfl_xor(s, 4); q += __shfl_xor(q, 4);
    float mk   = mask[row] ? 1.f : 0.f;
    float mean = mk * s * (1.f / 512.f);
    float msq  = mk * q * (1.f / 512.f);
    float rstd = rsqrtf(msq - mean * mean + 1e-5f);
#pragma unroll
    for (int c = 0; c < 16; ++c) {
      float4 g = ((const float4*)ln1g)[c * 8 + acg];
      float4 b = ((const float4*)ln1b)[c * 8 + acg];
      union { unsigned short us[4]; uint2 u; } pk;
      pk.us[0] = f2h(selu_f((f[c].x * mk - mean) * rstd * g.x + b.x));
      pk.us[1] = f2h(selu_f((f[c].y * mk - mean) * rstd * g.y + b.y));
      pk.us[2] = f2h(selu_f((f[c].z * mk - mean) * rstd * g.z + b.z));
      pk.us[3] = f2h(selu_f((f[c].w * mk - mean) * rstd * g.w + b.w));
      *(uint2*)&At[arow * LDA + c * 32 + acg * 4] = pk.u;
    }
    {
      union { unsigned short us[4]; uint2 u; } pk;
#pragma unroll
      for (int q2 = 0; q2 < 4; ++q2) {
        int kk = acg * 4 + q2;
        float val = 0.f;
        if (kk < 7)       val = jp[(size_t)row * 7 + kk];
        else if (kk < 14) val = jg[(size_t)row * 7 + kk - 7];
        pk.us[q2] = f2h(val);
      }
      *(uint2*)&At[arow * LDA + 512 + acg * 4] = pk.u;
    }
  }
  __syncthreads();

  f32x4 acc[4][4];
#pragma unroll
  for (int mi = 0; mi < 4; ++mi)
#pragma unroll
    for (int ni = 0; ni < 4; ++ni) acc[mi][ni] = (f32x4){0.f, 0.f, 0.f, 0.f};

  const unsigned short* aB = At + mrow * LDA + quad * 8;
  auto loadB = [&](f16x8* dst, int c) {
#pragma unroll
    for (int ni = 0; ni < 4; ++ni)
      dst[ni] = *(const f16x8*)(wBase + (size_t)(c * 4 + ni) * 512);
  };
  auto step = [&](const f16x8* bF, int c) {
    f16x8 a[4];
#pragma unroll
    for (int mi = 0; mi < 4; ++mi)
      a[mi] = *(const f16x8*)(aB + mi * 16 * LDA + c * 32);
#pragma unroll
    for (int mi = 0; mi < 4; ++mi)
#pragma unroll
      for (int ni = 0; ni < 4; ++ni)
        acc[mi][ni] = __builtin_amdgcn_mfma_f32_16x16x32_f16(a[mi], bF[ni], acc[mi][ni], 0, 0, 0);
  };
  for (int c = 0; c < KCHUNKS - 1; c += 2) {
    loadB(bO, c + 1);
    step(bE, c);
    loadB(bE, c + 2);
    step(bO, c + 1);
  }
  step(bE, 16);

  f16x8 bW2[2];
  bW2[0] = *(const f16x8*)&W2f[(size_t)(2 * wq)     * 512 + lane * 8];
  bW2[1] = *(const f16x8*)&W2f[(size_t)(2 * wq + 1) * 512 + lane * 8];

  float b1v[4], g2v[4], bl2v[4];
#pragma unroll
  for (int ni = 0; ni < 4; ++ni) {
    int col = wq * 64 + ni * 16 + mrow;
    b1v[ni] = b1[col]; g2v[ni] = ln2g[col]; bl2v[ni] = ln2b[col];
  }
#pragma unroll
  for (int mi = 0; mi < 4; ++mi)
#pragma unroll
    for (int reg = 0; reg < 4; ++reg) {
      int r = mi * 16 + quad * 4 + reg;
      float s = 0.f, q = 0.f;
#pragma unroll
      for (int ni = 0; ni < 4; ++ni) {
        float v = acc[mi][ni][reg] + b1v[ni];
        acc[mi][ni][reg] = v;
        s += v; q += v * v;
      }
      s += __shfl_xor(s, 1); q += __shfl_xor(q, 1);
      s += __shfl_xor(s, 2); q += __shfl_xor(q, 2);
      s += __shfl_xor(s, 4); q += __shfl_xor(q, 4);
      s += __shfl_xor(s, 8); q += __shfl_xor(q, 8);
      if ((lane & 15) == 0) { atomicAdd(&sm.rsum[r], s); atomicAdd(&sm.rsq[r], q); }
    }
  __syncthreads();
  if (tid < MTILE) {
    float mean = sm.rsum[tid] * (1.f / 512.f);
    float var  = sm.rsq[tid] * (1.f / 512.f) - mean * mean;
    sm.mean2[tid] = mean;
    sm.rstd2[tid] = rsqrtf(var + 1e-5f);
  }
  O[tid] = 0.f;
  __syncthreads();
#pragma unroll
  for (int mi = 0; mi < 4; ++mi)
#pragma unroll
    for (int ni = 0; ni < 4; ++ni)
#pragma unroll
      for (int reg = 0; reg < 4; ++reg) {
        int r = mi * 16 + quad * 4 + reg;
        int col = wq * 64 + ni * 16 + mrow;
        float v = (acc[mi][ni][reg] - sm.mean2[r]) * sm.rstd2[r] * g2v[ni] + bl2v[ni];
        X2[r * LDX + col] = f2h(selu_f(v));
      }
  __syncthreads();
  {
    f32x4 acc2[4];
#pragma unroll
    for (int mi = 0; mi < 4; ++mi) acc2[mi] = (f32x4){0.f, 0.f, 0.f, 0.f};
#pragma unroll
    for (int j = 0; j < 2; ++j) {
      int c2 = 2 * wq + j;
#pragma unroll
      for (int mi = 0; mi < 4; ++mi) {
        f16x8 a = *(const f16x8*)&X2[(mi * 16 + mrow) * LDX + c2 * 32 + quad * 8];
        acc2[mi] = __builtin_amdgcn_mfma_f32_16x16x32_f16(a, bW2[j], acc2[mi], 0, 0, 0);
      }
    }
#pragma unroll
    for (int mi = 0; mi < 4; ++mi)
#pragma unroll
      for (int reg = 0; reg < 4; ++reg)
        if (mrow < 7)
          atomicAdd(&O[(mi * 16 + quad * 4 + reg) * 8 + mrow], acc2[mi][reg]);
  }
  __syncthreads();
  {
    int r = tid >> 3, c = tid & 7;
    if (c < 7)
      out[(size_t)(m0 + r) * 7 + c] = tanhf(O[tid] + b2[c]);
  }
}

extern "C" void kernel_launch(void* const* d_in, const int* in_sizes, int n_in,
                              void* d_out, int out_size, void* d_ws, size_t ws_size,
                              hipStream_t stream) {
  const float* feat  = (const float*)d_in[0];
  const int*   crd   = (const int*)d_in[1];
  const float* jp    = (const float*)d_in[2];
  const float* jg    = (const float*)d_in[3];
  const float* ln1g  = (const float*)d_in[4];
  const float* ln1b  = (const float*)d_in[5];
  const float* W1    = (const float*)d_in[6];
  const float* b1    = (const float*)d_in[7];
  const float* ln2g  = (const float*)d_in[8];
  const float* ln2b  = (const float*)d_in[9];
  const float* W2    = (const float*)d_in[10];
  const float* b2    = (const float*)d_in[11];
  float* out = (float*)d_out;

  unsigned char*  mask = (unsigned char*)d_ws;
  unsigned short* W1f  = (unsigned short*)((char*)d_ws + W1F_OFF);
  unsigned short* W2f  = (unsigned short*)((char*)d_ws + W2F_OFF);
  unsigned short* X1   = (unsigned short*)((char*)d_ws + X1_OFF);

  hipMemsetAsync(mask, 0, (size_t)B_ROWS, stream);
  scatter_mask<<<B_ROWS / 256, 256, 0, stream>>>(crd, mask);
  build_wf<<<560, 512, 0, stream>>>(W1, W2, W1f, W2f);

  if (ws_size >= X1_OFF + X1_BYTES) {
    ln1_kernel<<<B_ROWS / 8, 512, 0, stream>>>(feat, mask, jp, jg, ln1g, ln1b, X1);
    actor_gemm<<<B_ROWS / MTILE, 512, 0, stream>>>(
        X1, W1f, b1, ln2g, ln2b, W2f, b2, out);
  } else {
    actor_fused<<<B_ROWS / MTILE, 512, 0, stream>>>(
        feat, mask, jp, jg, ln1g, ln1b, W1f, b1, ln2g, ln2b, W2f, b2, out);
  }
}

// Round 9
// 543.419 us; speedup vs baseline: 1.0777x; 1.0137x over previous
//
#include <hip/hip_runtime.h>

#define B_ROWS   131072
#define MTILE    64
#define KCHUNKS  17        // 544 / 32
#define LDA      552       // row stride f16: 544+8 pad (1104B: 16B-aligned, good LDS bank spread)
#define LDX      528       // X2 leading dim f16: 512+16 pad
// ws layout: [0,128KB) mask u8; W1f f16 [544 frags][512]; W2f f16 [16][512]; X1 f16 [B][552]
#define W1F_OFF  ((size_t)B_ROWS)
#define W2F_OFF  (W1F_OFF + (size_t)544 * 512 * 2)
#define X1_OFF   (W2F_OFF + (size_t)16 * 512 * 2)
#define X1_BYTES ((size_t)B_ROWS * LDA * 2)

typedef _Float16 f16x8 __attribute__((ext_vector_type(8)));
typedef float    f32x4 __attribute__((ext_vector_type(4)));
typedef float    fv4   __attribute__((ext_vector_type(4)));   // clang vec: legal for NT builtins
typedef unsigned int uv2 __attribute__((ext_vector_type(2))); // clang vec: legal for NT builtins

__device__ inline unsigned short f2h(float f) {
  _Float16 h = (_Float16)f;
  return __builtin_bit_cast(unsigned short, h);
}
__device__ inline float selu_f(float x) {
  const float lam = 1.0507009873554805f, alp = 1.6732632423543772f;
  return x > 0.f ? lam * x : lam * alp * (__expf(x) - 1.f);
}
// non-temporal global->LDS (aux=2 -> NT/SLC cpol bit): don't pollute L2 with the X1 stream
__device__ inline void gld16nt(const void* g, void* l) {
  __builtin_amdgcn_global_load_lds(
      (const __attribute__((address_space(1))) unsigned int*)g,
      (__attribute__((address_space(3))) unsigned int*)l, 16, 0, 2);
}

__global__ void scatter_mask(const int* __restrict__ coords,
                             unsigned char* __restrict__ mask) {
  int i = blockIdx.x * 256 + threadIdx.x;
  mask[coords[i]] = 1u;
}

// Blocks 0..543: W1 fp32 [526][512] -> W1f f16 pre-fragmented, per-wave MFMA order.
// Blocks 544..559: W2 fp32 [512][7] -> W2f f16 [16 kchunks][512], n padded to 16.
__global__ void build_wf(const float* __restrict__ W1, const float* __restrict__ W2,
                         unsigned short* __restrict__ W1f, unsigned short* __restrict__ W2f) {
  int tid = threadIdx.x;               // 0..511
  if (blockIdx.x < 544) {
    int fragIdx = blockIdx.x;
    int ni = fragIdx & 3;
    int c  = (fragIdx >> 2) % 17;
    int wq = fragIdx / 68;
    int nbase = wq * 64 + ni * 16;
    __shared__ float t[32][17];        // [k_local][n_local], +1 pad
    int kl = tid >> 4, nl = tid & 15;  // coalesced read side
    int kg = c * 32 + kl;
    float v = 0.f;
    if (kg < 512)      v = W1[(size_t)(kg + 14) * 512 + nbase + nl];
    else if (kg < 526) v = W1[(size_t)(kg - 512) * 512 + nbase + nl];
    t[kl][nl] = v;
    __syncthreads();
    int lane = tid >> 3, e = tid & 7;
    int k2 = ((lane >> 4) & 3) * 8 + e;
    int n2 = lane & 15;
    W1f[(size_t)fragIdx * 512 + tid] = f2h(t[k2][n2]);
  } else {
    int c2 = blockIdx.x - 544;         // 0..15
    int lane = tid >> 3, e = tid & 7;
    int n = lane & 15, quad = (lane >> 4) & 3;
    int k = c2 * 32 + quad * 8 + e;
    float v = (n < 7) ? W2[(size_t)k * 7 + n] : 0.f;
    W2f[(size_t)c2 * 512 + tid] = f2h(v);
  }
}

// ---------------- split path kernel 1: LN1+SELU+concat -> X1 f16 [B][552] ----------------
// One wave per row. No MFMA -> no AGPR reservation -> low reg pressure, no spill.
// feat reads + X1 writes are NON-TEMPORAL: both are touch-once streams; keeps L2/L3
// capacity for W1f (reused 2048x by actor_gemm).
__global__ __launch_bounds__(512) void ln1_kernel(
    const float* __restrict__ feat, const unsigned char* __restrict__ mask,
    const float* __restrict__ jp, const float* __restrict__ jg,
    const float* __restrict__ ln1g, const float* __restrict__ ln1b,
    unsigned short* __restrict__ X1) {
  const int w = threadIdx.x >> 6, lane = threadIdx.x & 63;
  const size_t row = (size_t)blockIdx.x * 8 + w;
  float mk = mask[row] ? 1.f : 0.f;    // masked-out row => y=0 => LN -> b -> selu(b)
  const fv4* frow = (const fv4*)feat + row * 128;
  fv4 f0 = __builtin_nontemporal_load(frow + lane);        // cols 4*lane..+4
  fv4 f1 = __builtin_nontemporal_load(frow + 64 + lane);   // cols 256+4*lane..+4
  float s = f0.x + f0.y + f0.z + f0.w + f1.x + f1.y + f1.z + f1.w;
  float q = f0.x * f0.x + f0.y * f0.y + f0.z * f0.z + f0.w * f0.w +
            f1.x * f1.x + f1.y * f1.y + f1.z * f1.z + f1.w * f1.w;
#pragma unroll
  for (int d = 32; d > 0; d >>= 1) { s += __shfl_xor(s, d); q += __shfl_xor(q, d); }
  float mean = mk * s * (1.f / 512.f);
  float msq  = mk * q * (1.f / 512.f);
  float rstd = rsqrtf(msq - mean * mean + 1e-5f);
  unsigned short* xr = X1 + row * LDA;
  {
    float4 g = ((const float4*)ln1g)[lane], b = ((const float4*)ln1b)[lane];
    union { unsigned short us[4]; uv2 u; } pk;
    pk.us[0] = f2h(selu_f((f0.x * mk - mean) * rstd * g.x + b.x));
    pk.us[1] = f2h(selu_f((f0.y * mk - mean) * rstd * g.y + b.y));
    pk.us[2] = f2h(selu_f((f0.z * mk - mean) * rstd * g.z + b.z));
    pk.us[3] = f2h(selu_f((f0.w * mk - mean) * rstd * g.w + b.w));
    __builtin_nontemporal_store(pk.u, (uv2*)&xr[lane * 4]);
  }
  {
    float4 g = ((const float4*)ln1g)[64 + lane], b = ((const float4*)ln1b)[64 + lane];
    union { unsigned short us[4]; uv2 u; } pk;
    pk.us[0] = f2h(selu_f((f1.x * mk - mean) * rstd * g.x + b.x));
    pk.us[1] = f2h(selu_f((f1.y * mk - mean) * rstd * g.y + b.y));
    pk.us[2] = f2h(selu_f((f1.z * mk - mean) * rstd * g.z + b.z));
    pk.us[3] = f2h(selu_f((f1.w * mk - mean) * rstd * g.w + b.w));
    __builtin_nontemporal_store(pk.u, (uv2*)&xr[256 + lane * 4]);
  }
  if (lane < 16) {       // jnt cols 512..543: jp[0..7), jg[7..14), zero pad
    int kk = 2 * lane;
    float v0 = 0.f, v1 = 0.f;
    if (kk < 7)       v0 = jp[row * 7 + kk];
    else if (kk < 14) v0 = jg[row * 7 + kk - 7];
    if (kk + 1 < 7)       v1 = jp[row * 7 + kk + 1];
    else if (kk + 1 < 14) v1 = jg[row * 7 + kk - 6];
    union { unsigned short us[2]; unsigned int u; } pj;
    pj.us[0] = f2h(v0); pj.us[1] = f2h(v1);
    __builtin_nontemporal_store(pj.u, (unsigned int*)&xr[512 + 2 * lane]);
  } else if (lane < 20) {  // zero the 544..551 pad (staged into LDS, never consumed)
    __builtin_nontemporal_store(0u, (unsigned int*)&xr[544 + 2 * (lane - 16)]);
  }
}

// ---------------- split path kernel 2: GEMM1 + LN2 + SELU + GEMM2 + tanh ----------------
struct __align__(16) SMemG {
  // union: At[64][552] f16 = 70656B (K loop; staged linearly via global_load_lds)
  //        X2[64][528] f16 = 67584B + O[64][8] f32 = 2048B (epilogue)
  char buf[70656];
  float part[8][MTILE][2];   // per-wave LN2 partial s,q
  float mean2[MTILE], rstd2[MTILE];
};

__global__ __launch_bounds__(512, 4) void actor_gemm(
    const unsigned short* __restrict__ X1,
    const unsigned short* __restrict__ W1f, const float* __restrict__ b1,
    const float* __restrict__ ln2g, const float* __restrict__ ln2b,
    const unsigned short* __restrict__ W2f, const float* __restrict__ b2,
    float* __restrict__ out) {
  __shared__ SMemG sm;
  unsigned short* At = (unsigned short*)sm.buf;            // [64][LDA] f16
  unsigned short* X2 = (unsigned short*)sm.buf;            // [64][LDX] f16 (epilogue union)
  float*          O  = (float*)(sm.buf + 64 * LDX * 2);    // [64][8] f32

  const int tid  = threadIdx.x;
  const int wq   = tid >> 6;   // wave 0..7 = N-slice (64 cols each)
  const int lane = tid & 63;
  const int m0   = blockIdx.x * MTILE;
  const int mrow = lane & 15;
  const int quad = lane >> 4;

  // ---------- A staging: linear 70656B copy, NON-TEMPORAL (don't evict W1f from L2) ----------
  {
    const char* src = (const char*)X1 + (size_t)m0 * (LDA * 2);
#pragma unroll
    for (int i = 0; i < 8; ++i) {
      int chunk = i * 8 + wq;
      gld16nt(src + (size_t)chunk * 1024 + lane * 16, (char*)sm.buf + chunk * 1024);
    }
    if (wq < 5) {
      int chunk = 64 + wq;
      gld16nt(src + (size_t)chunk * 1024 + lane * 16, (char*)sm.buf + chunk * 1024);
    }
  }

  // ---------- B chunk-0 prefetch (in flight alongside staging; normal/cached) ----------
  const unsigned short* wBase = W1f + (size_t)wq * 68 * 512 + lane * 8;
  f16x8 bE[4], bO[4];
#pragma unroll
  for (int ni = 0; ni < 4; ++ni)
    bE[ni] = *(const f16x8*)(wBase + (size_t)ni * 512);

  __syncthreads();  // barrier #1: staging (vmcnt drain) complete

  // ---------- K loop: barrier-free, pre-fragmented B, reg ping-pong ----------
  f32x4 acc[4][4];
#pragma unroll
  for (int mi = 0; mi < 4; ++mi)
#pragma unroll
    for (int ni = 0; ni < 4; ++ni) acc[mi][ni] = (f32x4){0.f, 0.f, 0.f, 0.f};

  const unsigned short* aB = At + mrow * LDA + quad * 8;

  auto loadB = [&](f16x8* dst, int c) {
#pragma unroll
    for (int ni = 0; ni < 4; ++ni)
      dst[ni] = *(const f16x8*)(wBase + (size_t)(c * 4 + ni) * 512);
  };
  auto step = [&](const f16x8* bF, int c) {
    f16x8 a[4];
#pragma unroll
    for (int mi = 0; mi < 4; ++mi)
      a[mi] = *(const f16x8*)(aB + mi * 16 * LDA + c * 32);
#pragma unroll
    for (int mi = 0; mi < 4; ++mi)
#pragma unroll
      for (int ni = 0; ni < 4; ++ni)
        acc[mi][ni] = __builtin_amdgcn_mfma_f32_16x16x32_f16(a[mi], bF[ni], acc[mi][ni], 0, 0, 0);
  };

  for (int c = 0; c < KCHUNKS - 1; c += 2) {  // c = 0,2,...,14
    loadB(bO, c + 1);
    step(bE, c);
    loadB(bE, c + 2);                         // c+2 <= 16, valid
    step(bO, c + 1);
  }
  step(bE, 16);

  // ---------- GEMM2 B-frag prefetch (wave's own K-slice k = wq*64..+64) ----------
  f16x8 bW2[2];
  bW2[0] = *(const f16x8*)&W2f[(size_t)(2 * wq)     * 512 + lane * 8];
  bW2[1] = *(const f16x8*)&W2f[(size_t)(2 * wq + 1) * 512 + lane * 8];

  // ---------- epilogue: +b1, LN2 stats (per-wave partials) ----------
  float b1v[4], g2v[4], bl2v[4];
#pragma unroll
  for (int ni = 0; ni < 4; ++ni) {
    int col = wq * 64 + ni * 16 + mrow;
    b1v[ni] = b1[col]; g2v[ni] = ln2g[col]; bl2v[ni] = ln2b[col];
  }
#pragma unroll
  for (int mi = 0; mi < 4; ++mi)
#pragma unroll
    for (int reg = 0; reg < 4; ++reg) {
      int r = mi * 16 + quad * 4 + reg;  // C/D layout: col=lane&15, row=quad*4+reg
      float s = 0.f, q = 0.f;
#pragma unroll
      for (int ni = 0; ni < 4; ++ni) {
        float v = acc[mi][ni][reg] + b1v[ni];
        acc[mi][ni][reg] = v;
        s += v; q += v * v;
      }
      s += __shfl_xor(s, 1); q += __shfl_xor(q, 1);
      s += __shfl_xor(s, 2); q += __shfl_xor(q, 2);
      s += __shfl_xor(s, 4); q += __shfl_xor(q, 4);
      s += __shfl_xor(s, 8); q += __shfl_xor(q, 8);
      if ((lane & 15) == 0) { sm.part[wq][r][0] = s; sm.part[wq][r][1] = q; }
    }
  __syncthreads();  // barrier #2: K-loop At reads done; partials complete
  if (tid < MTILE) {
    float s = 0.f, q = 0.f;
#pragma unroll
    for (int w = 0; w < 8; ++w) { s += sm.part[w][tid][0]; q += sm.part[w][tid][1]; }
    float mean = s * (1.f / 512.f);
    float var  = q * (1.f / 512.f) - mean * mean;
    sm.mean2[tid] = mean;
    sm.rstd2[tid] = rsqrtf(var + 1e-5f);
  }
  O[tid] = 0.f;     // 64x8 floats, region beyond X2, At dead
  __syncthreads();  // barrier #3: mean2/rstd2 + O ready
#pragma unroll
  for (int mi = 0; mi < 4; ++mi)
#pragma unroll
    for (int ni = 0; ni < 4; ++ni)
#pragma unroll
      for (int reg = 0; reg < 4; ++reg) {
        int r = mi * 16 + quad * 4 + reg;
        int col = wq * 64 + ni * 16 + mrow;
        float v = (acc[mi][ni][reg] - sm.mean2[r]) * sm.rstd2[r] * g2v[ni] + bl2v[ni];
        X2[r * LDX + col] = f2h(selu_f(v));
      }
  __syncthreads();  // barrier #4: X2 complete

  // ---------- GEMM2 (512->7) via MFMA, K-split across waves, LDS f32 reduce ----------
  {
    f32x4 acc2[4];
#pragma unroll
    for (int mi = 0; mi < 4; ++mi) acc2[mi] = (f32x4){0.f, 0.f, 0.f, 0.f};
#pragma unroll
    for (int j = 0; j < 2; ++j) {
      int c2 = 2 * wq + j;
#pragma unroll
      for (int mi = 0; mi < 4; ++mi) {
        f16x8 a = *(const f16x8*)&X2[(mi * 16 + mrow) * LDX + c2 * 32 + quad * 8];
        acc2[mi] = __builtin_amdgcn_mfma_f32_16x16x32_f16(a, bW2[j], acc2[mi], 0, 0, 0);
      }
    }
#pragma unroll
    for (int mi = 0; mi < 4; ++mi)
#pragma unroll
      for (int reg = 0; reg < 4; ++reg)
        if (mrow < 7)
          atomicAdd(&O[(mi * 16 + quad * 4 + reg) * 8 + mrow], acc2[mi][reg]);
  }
  __syncthreads();  // barrier #5: O complete
  {
    int r = tid >> 3, c = tid & 7;
    if (c < 7)
      out[(size_t)(m0 + r) * 7 + c] = tanhf(O[tid] + b2[c]);
  }
}

// ---------------- fallback: R4-verbatim fused kernel (used if ws too small for X1) ----------------
struct __align__(16) SMemF {
  char buf[70656];
  float rsum[MTILE], rsq[MTILE], mean2[MTILE], rstd2[MTILE];
};

__global__ __launch_bounds__(512, 4) void actor_fused(
    const float* __restrict__ feat, const unsigned char* __restrict__ mask,
    const float* __restrict__ jp, const float* __restrict__ jg,
    const float* __restrict__ ln1g, const float* __restrict__ ln1b,
    const unsigned short* __restrict__ W1f, const float* __restrict__ b1,
    const float* __restrict__ ln2g, const float* __restrict__ ln2b,
    const unsigned short* __restrict__ W2f, const float* __restrict__ b2,
    float* __restrict__ out) {
  __shared__ SMemF sm;
  unsigned short* At = (unsigned short*)sm.buf;
  unsigned short* X2 = (unsigned short*)sm.buf;
  float*          O  = (float*)(sm.buf + 64 * LDX * 2);

  const int tid  = threadIdx.x;
  const int wq   = tid >> 6;
  const int lane = tid & 63;
  const int m0   = blockIdx.x * MTILE;
  const int mrow = lane & 15;
  const int quad = lane >> 4;

  if (tid < MTILE) { sm.rsum[tid] = 0.f; sm.rsq[tid] = 0.f; }

  const unsigned short* wBase = W1f + (size_t)wq * 68 * 512 + lane * 8;
  f16x8 bE[4], bO[4];
#pragma unroll
  for (int ni = 0; ni < 4; ++ni)
    bE[ni] = *(const f16x8*)(wBase + (size_t)ni * 512);

  {
    const int arow = tid >> 3;
    const int acg  = tid & 7;
    const int row  = m0 + arow;
    const float4* frow = (const float4*)feat + (size_t)row * 128 + acg;
    float4 f[16];
    float s = 0.f, q = 0.f;
#pragma unroll
    for (int c = 0; c < 16; ++c) {
      float4 v = frow[(size_t)c * 8];
      f[c] = v;
      s += v.x + v.y + v.z + v.w;
      q += v.x * v.x + v.y * v.y + v.z * v.z + v.w * v.w;
    }
    s += __shfl_xor(s, 1); q += __shfl_xor(q, 1);
    s += __shfl_xor(s, 2); q += __shfl_xor(q, 2);
    s += __shfl_xor(s, 4); q += __shfl_xor(q, 4);
    float mk   = mask[row] ? 1.f : 0.f;
    float mean = mk * s * (1.f / 512.f);
    float msq  = mk * q * (1.f / 512.f);
    float rstd = rsqrtf(msq - mean * mean + 1e-5f);
#pragma unroll
    for (int c = 0; c < 16; ++c) {
      float4 g = ((const float4*)ln1g)[c * 8 + acg];
      float4 b = ((const float4*)ln1b)[c * 8 + acg];
      union { unsigned short us[4]; uint2 u; } pk;
      pk.us[0] = f2h(selu_f((f[c].x * mk - mean) * rstd * g.x + b.x));
      pk.us[1] = f2h(selu_f((f[c].y * mk - mean) * rstd * g.y + b.y));
      pk.us[2] = f2h(selu_f((f[c].z * mk - mean) * rstd * g.z + b.z));
      pk.us[3] = f2h(selu_f((f[c].w * mk - mean) * rstd * g.w + b.w));
      *(uint2*)&At[arow * LDA + c * 32 + acg * 4] = pk.u;
    }
    {
      union { unsigned short us[4]; uint2 u; } pk;
#pragma unroll
      for (int q2 = 0; q2 < 4; ++q2) {
        int kk = acg * 4 + q2;
        float val = 0.f;
        if (kk < 7)       val = jp[(size_t)row * 7 + kk];
        else if (kk < 14) val = jg[(size_t)row * 7 + kk - 7];
        pk.us[q2] = f2h(val);
      }
      *(uint2*)&At[arow * LDA + 512 + acg * 4] = pk.u;
    }
  }
  __syncthreads();

  f32x4 acc[4][4];
#pragma unroll
  for (int mi = 0; mi < 4; ++mi)
#pragma unroll
    for (int ni = 0; ni < 4; ++ni) acc[mi][ni] = (f32x4){0.f, 0.f, 0.f, 0.f};

  const unsigned short* aB = At + mrow * LDA + quad * 8;
  auto loadB = [&](f16x8* dst, int c) {
#pragma unroll
    for (int ni = 0; ni < 4; ++ni)
      dst[ni] = *(const f16x8*)(wBase + (size_t)(c * 4 + ni) * 512);
  };
  auto step = [&](const f16x8* bF, int c) {
    f16x8 a[4];
#pragma unroll
    for (int mi = 0; mi < 4; ++mi)
      a[mi] = *(const f16x8*)(aB + mi * 16 * LDA + c * 32);
#pragma unroll
    for (int mi = 0; mi < 4; ++mi)
#pragma unroll
      for (int ni = 0; ni < 4; ++ni)
        acc[mi][ni] = __builtin_amdgcn_mfma_f32_16x16x32_f16(a[mi], bF[ni], acc[mi][ni], 0, 0, 0);
  };
  for (int c = 0; c < KCHUNKS - 1; c += 2) {
    loadB(bO, c + 1);
    step(bE, c);
    loadB(bE, c + 2);
    step(bO, c + 1);
  }
  step(bE, 16);

  f16x8 bW2[2];
  bW2[0] = *(const f16x8*)&W2f[(size_t)(2 * wq)     * 512 + lane * 8];
  bW2[1] = *(const f16x8*)&W2f[(size_t)(2 * wq + 1) * 512 + lane * 8];

  float b1v[4], g2v[4], bl2v[4];
#pragma unroll
  for (int ni = 0; ni < 4; ++ni) {
    int col = wq * 64 + ni * 16 + mrow;
    b1v[ni] = b1[col]; g2v[ni] = ln2g[col]; bl2v[ni] = ln2b[col];
  }
#pragma unroll
  for (int mi = 0; mi < 4; ++mi)
#pragma unroll
    for (int reg = 0; reg < 4; ++reg) {
      int r = mi * 16 + quad * 4 + reg;
      float s = 0.f, q = 0.f;
#pragma unroll
      for (int ni = 0; ni < 4; ++ni) {
        float v = acc[mi][ni][reg] + b1v[ni];
        acc[mi][ni][reg] = v;
        s += v; q += v * v;
      }
      s += __shfl_xor(s, 1); q += __shfl_xor(q, 1);
      s += __shfl_xor(s, 2); q += __shfl_xor(q, 2);
      s += __shfl_xor(s, 4); q += __shfl_xor(q, 4);
      s += __shfl_xor(s, 8); q += __shfl_xor(q, 8);
      if ((lane & 15) == 0) { atomicAdd(&sm.rsum[r], s); atomicAdd(&sm.rsq[r], q); }
    }
  __syncthreads();
  if (tid < MTILE) {
    float mean = sm.rsum[tid] * (1.f / 512.f);
    float var  = sm.rsq[tid] * (1.f / 512.f) - mean * mean;
    sm.mean2[tid] = mean;
    sm.rstd2[tid] = rsqrtf(var + 1e-5f);
  }
  O[tid] = 0.f;
  __syncthreads();
#pragma unroll
  for (int mi = 0; mi < 4; ++mi)
#pragma unroll
    for (int ni = 0; ni < 4; ++ni)
#pragma unroll
      for (int reg = 0; reg < 4; ++reg) {
        int r = mi * 16 + quad * 4 + reg;
        int col = wq * 64 + ni * 16 + mrow;
        float v = (acc[mi][ni][reg] - sm.mean2[r]) * sm.rstd2[r] * g2v[ni] + bl2v[ni];
        X2[r * LDX + col] = f2h(selu_f(v));
      }
  __syncthreads();
  {
    f32x4 acc2[4];
#pragma unroll
    for (int mi = 0; mi < 4; ++mi) acc2[mi] = (f32x4){0.f, 0.f, 0.f, 0.f};
#pragma unroll
    for (int j = 0; j < 2; ++j) {
      int c2 = 2 * wq + j;
#pragma unroll
      for (int mi = 0; mi < 4; ++mi) {
        f16x8 a = *(const f16x8*)&X2[(mi * 16 + mrow) * LDX + c2 * 32 + quad * 8];
        acc2[mi] = __builtin_amdgcn_mfma_f32_16x16x32_f16(a, bW2[j], acc2[mi], 0, 0, 0);
      }
    }
#pragma unroll
    for (int mi = 0; mi < 4; ++mi)
#pragma unroll
      for (int reg = 0; reg < 4; ++reg)
        if (mrow < 7)
          atomicAdd(&O[(mi * 16 + quad * 4 + reg) * 8 + mrow], acc2[mi][reg]);
  }
  __syncthreads();
  {
    int r = tid >> 3, c = tid & 7;
    if (c < 7)
      out[(size_t)(m0 + r) * 7 + c] = tanhf(O[tid] + b2[c]);
  }
}

extern "C" void kernel_launch(void* const* d_in, const int* in_sizes, int n_in,
                              void* d_out, int out_size, void* d_ws, size_t ws_size,
                              hipStream_t stream) {
  const float* feat  = (const float*)d_in[0];
  const int*   crd   = (const int*)d_in[1];
  const float* jp    = (const float*)d_in[2];
  const float* jg    = (const float*)d_in[3];
  const float* ln1g  = (const float*)d_in[4];
  const float* ln1b  = (const float*)d_in[5];
  const float* W1    = (const float*)d_in[6];
  const float* b1    = (const float*)d_in[7];
  const float* ln2g  = (const float*)d_in[8];
  const float* ln2b  = (const float*)d_in[9];
  const float* W2    = (const float*)d_in[10];
  const float* b2    = (const float*)d_in[11];
  float* out = (float*)d_out;

  unsigned char*  mask = (unsigned char*)d_ws;
  unsigned short* W1f  = (unsigned short*)((char*)d_ws + W1F_OFF);
  unsigned short* W2f  = (unsigned short*)((char*)d_ws + W2F_OFF);
  unsigned short* X1   = (unsigned short*)((char*)d_ws + X1_OFF);

  (void)hipMemsetAsync(mask, 0, (size_t)B_ROWS, stream);
  scatter_mask<<<B_ROWS / 256, 256, 0, stream>>>(crd, mask);
  build_wf<<<560, 512, 0, stream>>>(W1, W2, W1f, W2f);

  if (ws_size >= X1_OFF + X1_BYTES) {
    ln1_kernel<<<B_ROWS / 8, 512, 0, stream>>>(feat, mask, jp, jg, ln1g, ln1b, X1);
    actor_gemm<<<B_ROWS / MTILE, 512, 0, stream>>>(
        X1, W1f, b1, ln2g, ln2b, W2f, b2, out);
  } else {
    actor_fused<<<B_ROWS / MTILE, 512, 0, stream>>>(
        feat, mask, jp, jg, ln1g, ln1b, W1f, b1, ln2g, ln2b, W2f, b2, out);
  }
}